// Round 3
// baseline (32684.549 us; speedup 1.0000x reference)
//
#include <hip/hip_runtime.h>
#include <hip/hip_bf16.h>

#define HDIM 1024
#define G3   3072
#define CHK  16
#define NEG_INF (-__builtin_inff())
#define EB   32    // encoder persistent blocks
#define DB   256   // decoder persistent blocks

typedef unsigned short u16;
typedef unsigned int   u32;

__device__ __forceinline__ float bf2f(u32 h){ union{u32 u; float f;} t; t.u = h<<16; return t.f; }

__device__ __forceinline__ float wred_sum(float v){
  #pragma unroll
  for(int o=32;o;o>>=1) v += __shfl_xor(v,o,64);
  return v;
}
__device__ __forceinline__ float wred_max(float v){
  #pragma unroll
  for(int o=32;o;o>>=1) v = fmaxf(v,__shfl_xor(v,o,64));
  return v;
}

// load 16 consecutive elements (weights, dtype per flag) into f32 regs
__device__ __forceinline__ void load16w(const void* W, long long eoff, int bf, float* x){
  if(bf){
    const uint4* q = (const uint4*)((const u16*)W + eoff);
    uint4 a = q[0], b = q[1];
    x[0]=bf2f(a.x&0xffffu); x[1]=bf2f(a.x>>16);
    x[2]=bf2f(a.y&0xffffu); x[3]=bf2f(a.y>>16);
    x[4]=bf2f(a.z&0xffffu); x[5]=bf2f(a.z>>16);
    x[6]=bf2f(a.w&0xffffu); x[7]=bf2f(a.w>>16);
    x[8]=bf2f(b.x&0xffffu); x[9]=bf2f(b.x>>16);
    x[10]=bf2f(b.y&0xffffu); x[11]=bf2f(b.y>>16);
    x[12]=bf2f(b.z&0xffffu); x[13]=bf2f(b.z>>16);
    x[14]=bf2f(b.w&0xffffu); x[15]=bf2f(b.w>>16);
  } else {
    const float4* q = (const float4*)((const float*)W + eoff);
    float4 A=q[0],B=q[1],C=q[2],D=q[3];
    x[0]=A.x;x[1]=A.y;x[2]=A.z;x[3]=A.w;
    x[4]=B.x;x[5]=B.y;x[6]=B.z;x[7]=B.w;
    x[8]=C.x;x[9]=C.y;x[10]=C.z;x[11]=C.w;
    x[12]=D.x;x[13]=D.y;x[14]=D.z;x[15]=D.w;
  }
}
__device__ __forceinline__ void load16f(const float* p, float* x){
  const float4* q=(const float4*)p;
  float4 A=q[0],B=q[1],C=q[2],D=q[3];
  x[0]=A.x;x[1]=A.y;x[2]=A.z;x[3]=A.w;
  x[4]=B.x;x[5]=B.y;x[6]=B.z;x[7]=B.w;
  x[8]=C.x;x[9]=C.y;x[10]=C.z;x[11]=C.w;
  x[12]=D.x;x[13]=D.y;x[14]=D.z;x[15]=D.w;
}
__device__ __forceinline__ float loadscal(const void* p, long long i, int bf){
  return bf ? bf2f(((const u16*)p)[i]) : ((const float*)p)[i];
}
__device__ __forceinline__ float sigf(float x){ return 1.f/(1.f+expf(-x)); }

__device__ __forceinline__ void dot4_accum(const float* w, const float xr[4][16], float a[4]){
  #pragma unroll
  for(int i=0;i<16;i++){
    a[0] += w[i]*xr[0][i];
    a[1] += w[i]*xr[1][i];
    a[2] += w[i]*xr[2][i];
    a[3] += w[i]*xr[3][i];
  }
}

// sorted-desc top4 insert, ties -> lower index (jax top_k semantics)
__device__ __forceinline__ void insert4(float* v, int* ix, float nv, int ni){
  bool b3 = (nv>v[3]) || (nv==v[3] && ni<ix[3]);
  if(!b3) return;
  bool b2 = (nv>v[2]) || (nv==v[2] && ni<ix[2]);
  bool b1 = (nv>v[1]) || (nv==v[1] && ni<ix[1]);
  bool b0 = (nv>v[0]) || (nv==v[0] && ni<ix[0]);
  if(b0){ v[3]=v[2];ix[3]=ix[2]; v[2]=v[1];ix[2]=ix[1]; v[1]=v[0];ix[1]=ix[0]; v[0]=nv;ix[0]=ni; }
  else if(b1){ v[3]=v[2];ix[3]=ix[2]; v[2]=v[1];ix[2]=ix[1]; v[1]=nv;ix[1]=ni; }
  else if(b2){ v[3]=v[2];ix[3]=ix[2]; v[2]=nv;ix[2]=ni; }
  else { v[3]=nv; ix[3]=ni; }
}
// merge two sorted-desc top4 lists
__device__ __forceinline__ void merge4(const float* va, const int* ia, const float* vb, const int* ib, float* vo, int* io){
  int pa=0, pb=0;
  for(int k=0;k<4;k++){
    bool ta;
    if(pa>=4) ta=false;
    else if(pb>=4) ta=true;
    else ta = (va[pa]>vb[pb]) || (va[pa]==vb[pb] && ia[pa]<ib[pb]);
    if(ta){ vo[k]=va[pa]; io[k]=ia[pa]; pa++; }
    else  { vo[k]=vb[pb]; io[k]=ib[pb]; pb++; }
  }
}

// simple grid barrier (encoder, 32 blocks, monotonic counter)
__device__ __forceinline__ void gbar(int* cnt, int nblk, int it){
  __syncthreads();
  if(threadIdx.x==0){
    __hip_atomic_fetch_add(cnt, 1, __ATOMIC_ACQ_REL, __HIP_MEMORY_SCOPE_AGENT);
    int target = nblk*it;
    while(__hip_atomic_load(cnt, __ATOMIC_ACQUIRE, __HIP_MEMORY_SCOPE_AGENT) < target)
      __builtin_amdgcn_s_sleep(1);
  }
  __syncthreads();
  __builtin_amdgcn_fence(__ATOMIC_ACQUIRE, "agent");
}

// striped grid barrier (decoder, DB=256 blocks): 8 arrival lines (32 adds each) + release word
__device__ __forceinline__ void gbar2(int* cnts, int* rel, int it){
  __syncthreads();
  if(threadIdx.x==0){
    int g = blockIdx.x & 7;
    __hip_atomic_fetch_add(&cnts[g*64], 1, __ATOMIC_ACQ_REL, __HIP_MEMORY_SCOPE_AGENT);
    if(blockIdx.x==0){
      #pragma unroll
      for(int g2=0; g2<8; ++g2){
        while(__hip_atomic_load(&cnts[g2*64], __ATOMIC_ACQUIRE, __HIP_MEMORY_SCOPE_AGENT) < 32*it)
          __builtin_amdgcn_s_sleep(1);
      }
      __hip_atomic_store(rel, it, __ATOMIC_RELEASE, __HIP_MEMORY_SCOPE_AGENT);
    } else {
      while(__hip_atomic_load(rel, __ATOMIC_ACQUIRE, __HIP_MEMORY_SCOPE_AGENT) < it)
        __builtin_amdgcn_s_sleep(1);
    }
  }
  __syncthreads();
  __builtin_amdgcn_fence(__ATOMIC_ACQUIRE, "agent");
}

// ---------------- dtype probe + barrier zeroing ----------------
__global__ __launch_bounds__(256) void k_probe(const u16* emb, int* flag, int* bar_cnt,
                                               int* dcnts, int* drel){
  __shared__ int cnt;
  if(threadIdx.x==0){ cnt=0; *bar_cnt=0; *drel=0; }
  for(int i=threadIdx.x;i<512;i+=256) dcnts[i]=0;
  __syncthreads();
  int c=0;
  for(int i=threadIdx.x;i<4096;i+=256){
    u32 e = (emb[i]>>7)&0xffu;
    if(e>=0x85u) c++;
  }
  atomicAdd(&cnt,c);
  __syncthreads();
  if(threadIdx.x==0) *flag = (cnt<100)?1:0;  // 1 = bf16, 0 = f32
}

// ---------------- encoder: gi = emb[seq] @ Wih^T + bih (batched over t) ----------------
__global__ __launch_bounds__(256) void k_enc_gi(const int* seq, const void* emb, const void* Wih,
                                                const void* bih, const int* flag, float* gi){
  int bf = *flag;
  int wg = blockIdx.x; int tg = wg>>3, rg = wg&7;
  int wave = threadIdx.x>>6, lane = threadIdx.x&63;
  int tok[4];
  #pragma unroll
  for(int j=0;j<4;j++) tok[j] = seq[tg*4+j];
  float xr[4][16];
  #pragma unroll
  for(int j=0;j<4;j++) load16w(emb, (long long)tok[j]*HDIM + lane*CHK, bf, xr[j]);
  for(int k=0;k<96;k++){
    int row = rg*384 + wave*96 + k;
    float w[16]; load16w(Wih, (long long)row*HDIM + lane*CHK, bf, w);
    float a[4]={0.f,0.f,0.f,0.f};
    dot4_accum(w, xr, a);
    float bias = loadscal(bih, row, bf);
    #pragma unroll
    for(int b=0;b<4;b++){
      float v = wred_sum(a[b]);
      if(lane==b) gi[(long long)(tg*4+b)*G3 + row] = v + bias;
    }
  }
}

// ---------------- persistent encoder recurrence: Whh held in registers ----------------
__global__ __launch_bounds__(512,2) void k_enc_persist(const void* Whh, const void* bhh,
                                                       const int* flag, const float* gi,
                                                       float* enc_out, int S, int* bar_cnt){
  int bf = *flag;
  int wave = threadIdx.x>>6, lane = threadIdx.x&63;
  int dbase = blockIdx.x*32;
  __shared__ float gh_s[96];
  __shared__ float bhh_s[96];
  if(threadIdx.x<96){
    int rl = threadIdx.x;
    int row = (rl>>5)*HDIM + dbase + (rl&31);
    bhh_s[rl] = loadscal(bhh, row, bf);
  }
  float wreg[12][16];
  #pragma unroll
  for(int k=0;k<12;k++){
    int rl = wave*12 + k;
    int row = (rl>>5)*HDIM + dbase + (rl&31);
    load16w(Whh, (long long)row*HDIM + lane*CHK, bf, wreg[k]);
  }
  __syncthreads();

  for(int t=0;t<S;t++){
    if(t>0) gbar(bar_cnt, EB, t);   // enc_out[t-1] fully published
    float h[16];
    if(t>0){
      load16f(enc_out + (long long)(t-1)*HDIM + lane*CHK, h);
    } else {
      #pragma unroll
      for(int i=0;i<16;i++) h[i]=0.f;
    }
    #pragma unroll
    for(int k=0;k<12;k++){
      float a=0.f;
      #pragma unroll
      for(int i=0;i<16;i++) a += wreg[k][i]*h[i];
      a = wred_sum(a);
      if(lane==k) gh_s[wave*12+k] = a + bhh_s[wave*12+k];
    }
    __syncthreads();
    if(threadIdx.x<32){
      int d = threadIdx.x;
      int gd = dbase + d;
      const float* gir = gi + (long long)t*G3;
      float ir = gir[gd], iz = gir[HDIM+gd], in_ = gir[2*HDIM+gd];
      float hr = gh_s[d], hz = gh_s[32+d], hn = gh_s[64+d];
      float r = sigf(ir+hr);
      float z = sigf(iz+hz);
      float n = tanhf(in_ + r*hn);
      float hp = (t>0) ? enc_out[(long long)(t-1)*HDIM + gd] : 0.f;
      enc_out[(long long)t*HDIM + gd] = (1.f-z)*n + z*hp;
    }
  }
}

// ---------------- persistent fused decoder: all 48 steps, 6 phases/step ----------------
__global__ __launch_bounds__(512,2) void k_dec_persist(
    const void* emb, const void* Wih, const void* Whh,
    const void* bih, const void* bhh, const void* Wc, const void* Wout,
    const int* flag, const float* enc_out, int S, int L, int V,
    float* h_cur, float* hnew, float* scoresb, float* ctx, float* concat,
    float* pm, float* ps, float* ptv, int* pti, int* cur_in,
    int* cnts, int* rel, void* dout)
{
  int bf = *flag;
  int t = threadIdx.x;
  int wave = t>>6, lane = t&63;
  int blk = blockIdx.x;

  __shared__ float gibuf[48], ghbuf[48];
  __shared__ float pbuf[1024];
  __shared__ float lm[32], lssum[32], ltv[128]; __shared__ int lti[128];
  // finalize (block 0 only)
  __shared__ float red[512];
  __shared__ float mtv[512*4]; __shared__ int mti[512*4];
  __shared__ float tpv[4][4]; __shared__ int tpi[4][4];
  __shared__ float logZ[4];
  __shared__ int l_bi[4], l_jj[4], l_tok[4]; __shared__ float l_ss[4], l_cum[4];
  __shared__ float cum_l[4];
  __shared__ int   tok_l[4*64]; __shared__ float shi_l[4*64];
  __shared__ int   otok[4*64];  __shared__ float oshi[4*64];
  __shared__ int bbest;

  // ---- prologue / init ----
  if(blk==0){
    const float* hf = enc_out + (long long)(S-1)*HDIM;
    for(int i=t;i<4*HDIM;i+=512) h_cur[i] = hf[i&(HDIM-1)];
    if(t<4){ cum_l[t]=0.f; cur_in[t]=1; }  // SOS=1
    for(int i=t;i<4*64;i+=512){ tok_l[i]=0; shi_l[i]=0.f; }
  }
  int bit = 0;
  gbar2(cnts, rel, ++bit);

  for(int st=0; st<L; ++st){
    // ======== phase A: decoder GRU (block owns 4 dims) ========
    {
      int base = blk*4;
      float xr[4][16];
      if(wave<4){
        int tok[4];
        #pragma unroll
        for(int b=0;b<4;b++) tok[b]=cur_in[b];
        #pragma unroll
        for(int b=0;b<4;b++) load16w(emb,(long long)tok[b]*HDIM+lane*CHK,bf,xr[b]);
        #pragma unroll
        for(int k=0;k<3;k++){
          int idx = wave*3+k; int g=idx>>2, d=idx&3;
          int row = g*HDIM + base + d;
          float w[16]; load16w(Wih,(long long)row*HDIM+lane*CHK,bf,w);
          float a[4]={0.f,0.f,0.f,0.f};
          dot4_accum(w,xr,a);
          float bias = loadscal(bih,row,bf);
          #pragma unroll
          for(int b=0;b<4;b++){
            float v = wred_sum(a[b]);
            if(lane==b) gibuf[idx*4+b] = v + bias;
          }
        }
      } else {
        #pragma unroll
        for(int b=0;b<4;b++) load16f(h_cur+(long long)b*HDIM+lane*CHK, xr[b]);
        #pragma unroll
        for(int k=0;k<3;k++){
          int idx = (wave-4)*3+k; int g=idx>>2, d=idx&3;
          int row = g*HDIM + base + d;
          float w[16]; load16w(Whh,(long long)row*HDIM+lane*CHK,bf,w);
          float a[4]={0.f,0.f,0.f,0.f};
          dot4_accum(w,xr,a);
          float bias = loadscal(bhh,row,bf);
          #pragma unroll
          for(int b=0;b<4;b++){
            float v = wred_sum(a[b]);
            if(lane==b) ghbuf[idx*4+b] = v + bias;
          }
        }
      }
      __syncthreads();
      if(t<16){
        int d=t&3, b=t>>2;
        float ir=gibuf[(0*4+d)*4+b], iz=gibuf[(1*4+d)*4+b], in_=gibuf[(2*4+d)*4+b];
        float hr=ghbuf[(0*4+d)*4+b], hz=ghbuf[(1*4+d)*4+b], hn=ghbuf[(2*4+d)*4+b];
        float r = sigf(ir+hr);
        float z = sigf(iz+hz);
        float n = tanhf(in_ + r*hn);
        float h = h_cur[b*HDIM + base + d];
        hnew[b*HDIM + base + d] = (1.f-z)*n + z*h;
      }
    }
    gbar2(cnts, rel, ++bit);

    // ======== phase B: attention scores (block = seq position) ========
    if(blk < S && wave < 4){
      float x[16]; load16f(hnew+(long long)wave*HDIM+lane*CHK, x);
      float e[16]; load16f(enc_out+(long long)blk*HDIM+lane*CHK, e);
      float a=0.f;
      #pragma unroll
      for(int i=0;i<16;i++) a += x[i]*e[i];
      a = wred_sum(a);
      if(lane==0) scoresb[blk*4+wave] = a;
    }
    gbar2(cnts, rel, ++bit);

    // ======== phase C: softmax + context (blocks 0..7, 128 dims each) ========
    if(blk < 8){
      pbuf[t]       = scoresb[t];
      pbuf[t+512]   = scoresb[t+512];
      __syncthreads();
      if(wave<4){
        int b = wave;
        float v[4];
        #pragma unroll
        for(int k=0;k<4;k++) v[k]=pbuf[(lane+64*k)*4+b];
        float m = fmaxf(fmaxf(v[0],v[1]),fmaxf(v[2],v[3]));
        m = wred_max(m);
        float e[4]; float ss=0.f;
        #pragma unroll
        for(int k=0;k<4;k++){ e[k]=expf(v[k]-m); ss+=e[k]; }
        ss = wred_sum(ss);
        #pragma unroll
        for(int k=0;k<4;k++) pbuf[(lane+64*k)*4+b] = e[k]/ss;
      }
      __syncthreads();
      int hl = t>>2, b = t&3;
      int h = blk*128 + hl;
      float a = 0.f;
      #pragma unroll 8
      for(int s=0;s<256;s++) a += pbuf[s*4+b]*enc_out[(long long)s*HDIM + h];
      ctx[b*HDIM+h] = a;
    }
    gbar2(cnts, rel, ++bit);

    // ======== phase D: concat @ Wc^T, tanh (block owns 4 rows) ========
    {
      int r = blk*4 + (wave>>1);
      int b0 = (wave&1)*2;
      float acc0=0.f, acc1=0.f;
      {
        float w[16]; load16w(Wc,(long long)r*2048 + lane*CHK, bf, w);
        float x0[16], x1[16];
        load16f(hnew+(long long)b0*HDIM+lane*CHK, x0);
        load16f(hnew+(long long)(b0+1)*HDIM+lane*CHK, x1);
        #pragma unroll
        for(int i=0;i<16;i++){ acc0+=w[i]*x0[i]; acc1+=w[i]*x1[i]; }
      }
      {
        float w[16]; load16w(Wc,(long long)r*2048 + 1024 + lane*CHK, bf, w);
        float x0[16], x1[16];
        load16f(ctx+(long long)b0*HDIM+lane*CHK, x0);
        load16f(ctx+(long long)(b0+1)*HDIM+lane*CHK, x1);
        #pragma unroll
        for(int i=0;i<16;i++){ acc0+=w[i]*x0[i]; acc1+=w[i]*x1[i]; }
      }
      acc0 = wred_sum(acc0); acc1 = wred_sum(acc1);
      if(lane==0){
        concat[b0*HDIM + r]     = tanhf(acc0);
        concat[(b0+1)*HDIM + r] = tanhf(acc1);
      }
    }
    gbar2(cnts, rel, ++bit);

    // ======== phase E: Wout logits + per-block online max/sumexp/top4 ========
    {
      float xr[4][16];
      #pragma unroll
      for(int b=0;b<4;b++) load16f(concat+(long long)b*HDIM+lane*CHK, xr[b]);
      int wbase = blk*125;
      int off  = (wave<5) ? wave*16 : 80 + (wave-5)*15;   // 5x16 + 3x15 = 125
      int cnt  = (wave<5) ? 16 : 15;
      float m[4], s[4], tv[4][4]; int ti_[4][4];
      #pragma unroll
      for(int b=0;b<4;b++){
        m[b]=NEG_INF; s[b]=0.f;
        #pragma unroll
        for(int j=0;j<4;j++){ tv[b][j]=NEG_INF; ti_[b][j]=0; }
      }
      for(int k=0;k<cnt;k++){
        int row = wbase + off + k;
        if(row>=V) break;
        float w[16]; load16w(Wout,(long long)row*HDIM+lane*CHK,bf,w);
        float a[4]={0.f,0.f,0.f,0.f};
        dot4_accum(w,xr,a);
        a[0]=wred_sum(a[0]); a[1]=wred_sum(a[1]); a[2]=wred_sum(a[2]); a[3]=wred_sum(a[3]);
        if(lane==0){
          #pragma unroll
          for(int b=0;b<4;b++){
            float v = a[b];
            if(v>m[b]){ s[b]=s[b]*expf(m[b]-v)+1.f; m[b]=v; }
            else s[b] += expf(v-m[b]);
            insert4(tv[b], ti_[b], v, row);
          }
        }
      }
      if(lane==0){
        #pragma unroll
        for(int b=0;b<4;b++){
          lm[wave*4+b]=m[b]; lssum[wave*4+b]=s[b];
          #pragma unroll
          for(int j=0;j<4;j++){ ltv[(wave*4+b)*4+j]=tv[b][j]; lti[(wave*4+b)*4+j]=ti_[b][j]; }
        }
      }
      __syncthreads();
      if(t==0){
        for(int b=0;b<4;b++){
          float M=NEG_INF;
          for(int w=0;w<8;w++) M=fmaxf(M,lm[w*4+b]);
          float Ssum=0.f;
          for(int w=0;w<8;w++) Ssum += lssum[w*4+b]*expf(lm[w*4+b]-M);
          float cv[4]; int ci[4];
          for(int j=0;j<4;j++){ cv[j]=ltv[(0*4+b)*4+j]; ci[j]=lti[(0*4+b)*4+j]; }
          for(int w=1;w<8;w++){
            float vo[4]; int io[4];
            merge4(cv,ci,&ltv[(w*4+b)*4],&lti[(w*4+b)*4],vo,io);
            for(int j=0;j<4;j++){ cv[j]=vo[j]; ci[j]=io[j]; }
          }
          pm[blk*4+b]=M; ps[blk*4+b]=Ssum;
          for(int j=0;j<4;j++){ ptv[(blk*4+b)*4+j]=cv[j]; pti[(blk*4+b)*4+j]=ci[j]; }
        }
      }
    }
    gbar2(cnts, rel, ++bit);

    // ======== phase F: finalize + beam update (block 0) ========
    if(blk==0){
      for(int b=0;b<4;b++){
        float v = (t<256) ? pm[t*4+b] : NEG_INF;
        red[t]=v; __syncthreads();
        for(int sp=256;sp;sp>>=1){ if(t<sp) red[t]=fmaxf(red[t],red[t+sp]); __syncthreads(); }
        float M = red[0]; __syncthreads();
        red[t] = (t<256) ? ps[t*4+b]*expf(v-M) : 0.f; __syncthreads();
        for(int sp=256;sp;sp>>=1){ if(t<sp) red[t]+=red[t+sp]; __syncthreads(); }
        if(t==0) logZ[b]=M+logf(red[0]);
        __syncthreads();
      }
      for(int b=0;b<4;b++){
        if(t<256){
          for(int j=0;j<4;j++){ mtv[t*4+j]=ptv[(t*4+b)*4+j]; mti[t*4+j]=pti[(t*4+b)*4+j]; }
        } else {
          for(int j=0;j<4;j++){ mtv[t*4+j]=NEG_INF; mti[t*4+j]=0; }
        }
        __syncthreads();
        for(int sp=1; sp<512; sp<<=1){
          if((t & (2*sp-1))==0 && t+sp<512){
            float vo[4]; int io[4];
            merge4(&mtv[t*4], &mti[t*4], &mtv[(t+sp)*4], &mti[(t+sp)*4], vo, io);
            for(int j=0;j<4;j++){ mtv[t*4+j]=vo[j]; mti[t*4+j]=io[j]; }
          }
          __syncthreads();
        }
        if(t<4){ tpv[b][t]=mtv[t]-logZ[b]; tpi[b][t]=mti[t]; }
        __syncthreads();
      }
      if(t==0){
        float oc[4];
        for(int b=0;b<4;b++) oc[b]=cum_l[b];
        float cand[16];
        for(int b=0;b<4;b++)
          for(int j=0;j<4;j++){
            bool valid = (st>0)||(b==0);
            cand[b*4+j] = valid ? oc[b]+tpv[b][j] : NEG_INF;
          }
        bool used[16];
        for(int i=0;i<16;i++) used[i]=false;
        for(int q=0;q<4;q++){
          int best=0; float bv=NEG_INF;
          for(int i=0;i<16;i++){ if(!used[i] && cand[i]>bv){ bv=cand[i]; best=i; } }
          used[best]=true;
          int bi = best>>2, jj = best&3;
          l_bi[q]=bi; l_jj[q]=jj; l_tok[q]=tpi[bi][jj]; l_ss[q]=tpv[bi][jj]; l_cum[q]=bv;
        }
      }
      __syncthreads();
      for(int i=t;i<4*L;i+=512){ otok[i]=tok_l[i]; oshi[i]=shi_l[i]; }
      __syncthreads();
      for(int i=t;i<4*L;i+=512){
        int q=i/L, c=i%L;
        int src=l_bi[q];
        tok_l[i] = (c==st)? l_tok[q] : otok[src*L+c];
        shi_l[i] = (c==st)? l_ss[q]  : oshi[src*L+c];
      }
      if(t<4){ cum_l[t]=l_cum[t]; cur_in[t]=l_tok[t]; }
      for(int i=t;i<4*HDIM;i+=512){
        int q=i>>10;
        h_cur[i] = hnew[l_jj[q]*HDIM + (i&(HDIM-1))];
      }
      if(st==L-1){
        if(t==0){
          int bb=0; float bv=l_cum[0];
          for(int b=1;b<4;b++) if(l_cum[b]>bv){ bv=l_cum[b]; bb=b; }
          bbest=bb;
        }
        __syncthreads();
        int bb=bbest;
        for(int c=t;c<L;c+=512){
          float tokv = (float)((c==st)? l_tok[bb] : otok[l_bi[bb]*L+c]);
          float shv  = (c==st)? l_ss[bb] : oshi[l_bi[bb]*L+c];
          if(bf){
            __hip_bfloat16* o = (__hip_bfloat16*)dout;
            o[c]   = __float2bfloat16(tokv);
            o[L+c] = __float2bfloat16(shv);
          } else {
            float* o = (float*)dout;
            o[c]   = tokv;
            o[L+c] = shv;
          }
        }
      }
    }
    gbar2(cnts, rel, ++bit);
  }
}

extern "C" void kernel_launch(void* const* d_in, const int* in_sizes, int n_in,
                              void* d_out, int out_size, void* d_ws, size_t ws_size,
                              hipStream_t stream) {
  const int* seq   = (const int*)d_in[0];
  const void* emb  = d_in[3];
  const void* eWih = d_in[4]; const void* eWhh = d_in[5];
  const void* ebih = d_in[6]; const void* ebhh = d_in[7];
  const void* dWih = d_in[8]; const void* dWhh = d_in[9];
  const void* dbih = d_in[10]; const void* dbhh = d_in[11];
  const void* Wc   = d_in[12]; const void* Wout = d_in[13];

  int S = in_sizes[0];        // 256
  int L = out_size/2;         // 48
  int V = in_sizes[13]/HDIM;  // 32000

  char* p = (char*)d_ws;
  auto carve = [&](size_t bytes)->void* {
    void* r = (void*)p;
    p += (bytes + 255) & ~(size_t)255;
    return r;
  };
  int*   flag    = (int*)  carve(4);
  int*   bar_cnt = (int*)  carve(4);
  int*   dcnts   = (int*)  carve(512*4);   // 8 lines x 64 ints
  int*   drel    = (int*)  carve(64*4);
  float* gi_enc  = (float*)carve((size_t)S*G3*4);
  float* enc_out = (float*)carve((size_t)S*HDIM*4);
  float* h_cur   = (float*)carve(4*HDIM*4);
  float* hnew    = (float*)carve(4*HDIM*4);
  float* scoresb = (float*)carve((size_t)S*4*4);
  float* ctx     = (float*)carve(4*HDIM*4);
  float* concat  = (float*)carve(4*HDIM*4);
  float* pm      = (float*)carve(256*4*4);
  float* ps      = (float*)carve(256*4*4);
  float* ptv     = (float*)carve(256*16*4);
  int*   pti     = (int*)  carve(256*16*4);
  int*   cur_in  = (int*)  carve(4*4);

  k_probe<<<1,256,0,stream>>>((const u16*)emb, flag, bar_cnt, dcnts, drel);
  k_enc_gi<<<(S/4)*8,256,0,stream>>>(seq, emb, eWih, ebih, flag, gi_enc);
  k_enc_persist<<<EB,512,0,stream>>>(eWhh, ebhh, flag, gi_enc, enc_out, S, bar_cnt);
  k_dec_persist<<<DB,512,0,stream>>>(emb, dWih, dWhh, dbih, dbhh, Wc, Wout,
                                     flag, enc_out, S, L, V,
                                     h_cur, hnew, scoresb, ctx, concat,
                                     pm, ps, ptv, pti, cur_in,
                                     dcnts, drel, d_out);
}

// Round 4
// 16210.567 us; speedup vs baseline: 2.0162x; 2.0162x over previous
//
#include <hip/hip_runtime.h>
#include <hip/hip_bf16.h>

#define HDIM 1024
#define G3   3072
#define CHK  16
#define NEG_INF (-__builtin_inff())
#define EB   32    // encoder persistent blocks
#define DB   256   // decoder persistent blocks

typedef unsigned short u16;
typedef unsigned int   u32;

__device__ __forceinline__ float bf2f(u32 h){ union{u32 u; float f;} t; t.u = h<<16; return t.f; }

__device__ __forceinline__ float wred_sum(float v){
  #pragma unroll
  for(int o=32;o;o>>=1) v += __shfl_xor(v,o,64);
  return v;
}
__device__ __forceinline__ float wred_max(float v){
  #pragma unroll
  for(int o=32;o;o>>=1) v = fmaxf(v,__shfl_xor(v,o,64));
  return v;
}

// load 16 consecutive elements (weights, dtype per flag) into f32 regs
__device__ __forceinline__ void load16w(const void* W, long long eoff, int bf, float* x){
  if(bf){
    const uint4* q = (const uint4*)((const u16*)W + eoff);
    uint4 a = q[0], b = q[1];
    x[0]=bf2f(a.x&0xffffu); x[1]=bf2f(a.x>>16);
    x[2]=bf2f(a.y&0xffffu); x[3]=bf2f(a.y>>16);
    x[4]=bf2f(a.z&0xffffu); x[5]=bf2f(a.z>>16);
    x[6]=bf2f(a.w&0xffffu); x[7]=bf2f(a.w>>16);
    x[8]=bf2f(b.x&0xffffu); x[9]=bf2f(b.x>>16);
    x[10]=bf2f(b.y&0xffffu); x[11]=bf2f(b.y>>16);
    x[12]=bf2f(b.z&0xffffu); x[13]=bf2f(b.z>>16);
    x[14]=bf2f(b.w&0xffffu); x[15]=bf2f(b.w>>16);
  } else {
    const float4* q = (const float4*)((const float*)W + eoff);
    float4 A=q[0],B=q[1],C=q[2],D=q[3];
    x[0]=A.x;x[1]=A.y;x[2]=A.z;x[3]=A.w;
    x[4]=B.x;x[5]=B.y;x[6]=B.z;x[7]=B.w;
    x[8]=C.x;x[9]=C.y;x[10]=C.z;x[11]=C.w;
    x[12]=D.x;x[13]=D.y;x[14]=D.z;x[15]=D.w;
  }
}
__device__ __forceinline__ void load16f(const float* p, float* x){
  const float4* q=(const float4*)p;
  float4 A=q[0],B=q[1],C=q[2],D=q[3];
  x[0]=A.x;x[1]=A.y;x[2]=A.z;x[3]=A.w;
  x[4]=B.x;x[5]=B.y;x[6]=B.z;x[7]=B.w;
  x[8]=C.x;x[9]=C.y;x[10]=C.z;x[11]=C.w;
  x[12]=D.x;x[13]=D.y;x[14]=D.z;x[15]=D.w;
}
__device__ __forceinline__ float loadscal(const void* p, long long i, int bf){
  return bf ? bf2f(((const u16*)p)[i]) : ((const float*)p)[i];
}
__device__ __forceinline__ float sigf(float x){ return 1.f/(1.f+expf(-x)); }

__device__ __forceinline__ void dot4_accum(const float* w, const float xr[4][16], float a[4]){
  #pragma unroll
  for(int i=0;i<16;i++){
    a[0] += w[i]*xr[0][i];
    a[1] += w[i]*xr[1][i];
    a[2] += w[i]*xr[2][i];
    a[3] += w[i]*xr[3][i];
  }
}

// sorted-desc top4 insert, ties -> lower index (jax top_k semantics)
__device__ __forceinline__ void insert4(float* v, int* ix, float nv, int ni){
  bool b3 = (nv>v[3]) || (nv==v[3] && ni<ix[3]);
  if(!b3) return;
  bool b2 = (nv>v[2]) || (nv==v[2] && ni<ix[2]);
  bool b1 = (nv>v[1]) || (nv==v[1] && ni<ix[1]);
  bool b0 = (nv>v[0]) || (nv==v[0] && ni<ix[0]);
  if(b0){ v[3]=v[2];ix[3]=ix[2]; v[2]=v[1];ix[2]=ix[1]; v[1]=v[0];ix[1]=ix[0]; v[0]=nv;ix[0]=ni; }
  else if(b1){ v[3]=v[2];ix[3]=ix[2]; v[2]=v[1];ix[2]=ix[1]; v[1]=nv;ix[1]=ni; }
  else if(b2){ v[3]=v[2];ix[3]=ix[2]; v[2]=nv;ix[2]=ni; }
  else { v[3]=nv; ix[3]=ni; }
}
// merge two sorted-desc top4 lists
__device__ __forceinline__ void merge4(const float* va, const int* ia, const float* vb, const int* ib, float* vo, int* io){
  int pa=0, pb=0;
  for(int k=0;k<4;k++){
    bool ta;
    if(pa>=4) ta=false;
    else if(pb>=4) ta=true;
    else ta = (va[pa]>vb[pb]) || (va[pa]==vb[pb] && ia[pa]<ib[pb]);
    if(ta){ vo[k]=va[pa]; io[k]=ia[pa]; pa++; }
    else  { vo[k]=vb[pb]; io[k]=ib[pb]; pb++; }
  }
}

// grid barrier (encoder, 32 blocks): relaxed atomics, single release/acquire fences
__device__ __forceinline__ void gbar(int* cnt, int nblk, int it){
  __syncthreads();
  if(threadIdx.x==0){
    __builtin_amdgcn_fence(__ATOMIC_RELEASE, "agent");   // publish this block's writes (once)
    __hip_atomic_fetch_add(cnt, 1, __ATOMIC_RELAXED, __HIP_MEMORY_SCOPE_AGENT);
    int target = nblk*it;
    while(__hip_atomic_load(cnt, __ATOMIC_RELAXED, __HIP_MEMORY_SCOPE_AGENT) < target)
      __builtin_amdgcn_s_sleep(1);
  }
  __syncthreads();
  __builtin_amdgcn_fence(__ATOMIC_ACQUIRE, "agent");     // invalidate stale caches (once)
}

// striped grid barrier (decoder, DB=256 blocks): 8 arrival lines + release word.
// All polling via RELAXED agent atomics (cache-bypassing loads, no per-iteration
// cache maintenance); exactly one release fence at arrival and one acquire fence
// after completion.
__device__ __forceinline__ void gbar2(int* cnts, int* rel, int it){
  __syncthreads();
  if(threadIdx.x==0){
    int g = blockIdx.x & 7;
    __builtin_amdgcn_fence(__ATOMIC_RELEASE, "agent");   // publish this block's writes (once)
    __hip_atomic_fetch_add(&cnts[g*64], 1, __ATOMIC_RELAXED, __HIP_MEMORY_SCOPE_AGENT);
    if(blockIdx.x==0){
      #pragma unroll
      for(int g2=0; g2<8; ++g2){
        while(__hip_atomic_load(&cnts[g2*64], __ATOMIC_RELAXED, __HIP_MEMORY_SCOPE_AGENT) < 32*it)
          __builtin_amdgcn_s_sleep(1);
      }
      // RELEASE: orders after the poll loads; one wbl2 from a single CU
      __hip_atomic_store(rel, it, __ATOMIC_RELEASE, __HIP_MEMORY_SCOPE_AGENT);
    } else {
      while(__hip_atomic_load(rel, __ATOMIC_RELAXED, __HIP_MEMORY_SCOPE_AGENT) < it)
        __builtin_amdgcn_s_sleep(1);
    }
  }
  __syncthreads();
  __builtin_amdgcn_fence(__ATOMIC_ACQUIRE, "agent");     // invalidate stale caches (once)
}

// ---------------- dtype probe + barrier zeroing ----------------
__global__ __launch_bounds__(256) void k_probe(const u16* emb, int* flag, int* bar_cnt,
                                               int* dcnts, int* drel){
  __shared__ int cnt;
  if(threadIdx.x==0){ cnt=0; *bar_cnt=0; *drel=0; }
  for(int i=threadIdx.x;i<512;i+=256) dcnts[i]=0;
  __syncthreads();
  int c=0;
  for(int i=threadIdx.x;i<4096;i+=256){
    u32 e = (emb[i]>>7)&0xffu;
    if(e>=0x85u) c++;
  }
  atomicAdd(&cnt,c);
  __syncthreads();
  if(threadIdx.x==0) *flag = (cnt<100)?1:0;  // 1 = bf16, 0 = f32
}

// ---------------- encoder: gi = emb[seq] @ Wih^T + bih (batched over t) ----------------
__global__ __launch_bounds__(256) void k_enc_gi(const int* seq, const void* emb, const void* Wih,
                                                const void* bih, const int* flag, float* gi){
  int bf = *flag;
  int wg = blockIdx.x; int tg = wg>>3, rg = wg&7;
  int wave = threadIdx.x>>6, lane = threadIdx.x&63;
  int tok[4];
  #pragma unroll
  for(int j=0;j<4;j++) tok[j] = seq[tg*4+j];
  float xr[4][16];
  #pragma unroll
  for(int j=0;j<4;j++) load16w(emb, (long long)tok[j]*HDIM + lane*CHK, bf, xr[j]);
  for(int k=0;k<96;k++){
    int row = rg*384 + wave*96 + k;
    float w[16]; load16w(Wih, (long long)row*HDIM + lane*CHK, bf, w);
    float a[4]={0.f,0.f,0.f,0.f};
    dot4_accum(w, xr, a);
    float bias = loadscal(bih, row, bf);
    #pragma unroll
    for(int b=0;b<4;b++){
      float v = wred_sum(a[b]);
      if(lane==b) gi[(long long)(tg*4+b)*G3 + row] = v + bias;
    }
  }
}

// ---------------- persistent encoder recurrence: Whh held in registers ----------------
__global__ __launch_bounds__(512,2) void k_enc_persist(const void* Whh, const void* bhh,
                                                       const int* flag, const float* gi,
                                                       float* enc_out, int S, int* bar_cnt){
  int bf = *flag;
  int wave = threadIdx.x>>6, lane = threadIdx.x&63;
  int dbase = blockIdx.x*32;
  __shared__ float gh_s[96];
  __shared__ float bhh_s[96];
  if(threadIdx.x<96){
    int rl = threadIdx.x;
    int row = (rl>>5)*HDIM + dbase + (rl&31);
    bhh_s[rl] = loadscal(bhh, row, bf);
  }
  float wreg[12][16];
  #pragma unroll
  for(int k=0;k<12;k++){
    int rl = wave*12 + k;
    int row = (rl>>5)*HDIM + dbase + (rl&31);
    load16w(Whh, (long long)row*HDIM + lane*CHK, bf, wreg[k]);
  }
  __syncthreads();

  for(int t=0;t<S;t++){
    if(t>0) gbar(bar_cnt, EB, t);   // enc_out[t-1] fully published
    float h[16];
    if(t>0){
      load16f(enc_out + (long long)(t-1)*HDIM + lane*CHK, h);
    } else {
      #pragma unroll
      for(int i=0;i<16;i++) h[i]=0.f;
    }
    #pragma unroll
    for(int k=0;k<12;k++){
      float a=0.f;
      #pragma unroll
      for(int i=0;i<16;i++) a += wreg[k][i]*h[i];
      a = wred_sum(a);
      if(lane==k) gh_s[wave*12+k] = a + bhh_s[wave*12+k];
    }
    __syncthreads();
    if(threadIdx.x<32){
      int d = threadIdx.x;
      int gd = dbase + d;
      const float* gir = gi + (long long)t*G3;
      float ir = gir[gd], iz = gir[HDIM+gd], in_ = gir[2*HDIM+gd];
      float hr = gh_s[d], hz = gh_s[32+d], hn = gh_s[64+d];
      float r = sigf(ir+hr);
      float z = sigf(iz+hz);
      float n = tanhf(in_ + r*hn);
      float hp = (t>0) ? enc_out[(long long)(t-1)*HDIM + gd] : 0.f;
      enc_out[(long long)t*HDIM + gd] = (1.f-z)*n + z*hp;
    }
  }
}

// ---------------- persistent fused decoder: all 48 steps, 6 phases/step ----------------
__global__ __launch_bounds__(512,2) void k_dec_persist(
    const void* emb, const void* Wih, const void* Whh,
    const void* bih, const void* bhh, const void* Wc, const void* Wout,
    const int* flag, const float* enc_out, int S, int L, int V,
    float* h_cur, float* hnew, float* scoresb, float* ctx, float* concat,
    float* pm, float* ps, float* ptv, int* pti, int* cur_in,
    int* cnts, int* rel, void* dout)
{
  int bf = *flag;
  int t = threadIdx.x;
  int wave = t>>6, lane = t&63;
  int blk = blockIdx.x;

  __shared__ float gibuf[48], ghbuf[48];
  __shared__ float pbuf[1024];
  __shared__ float lm[32], lssum[32], ltv[128]; __shared__ int lti[128];
  // finalize (block 0 only)
  __shared__ float red[512];
  __shared__ float mtv[512*4]; __shared__ int mti[512*4];
  __shared__ float tpv[4][4]; __shared__ int tpi[4][4];
  __shared__ float logZ[4];
  __shared__ int l_bi[4], l_jj[4], l_tok[4]; __shared__ float l_ss[4], l_cum[4];
  __shared__ float cum_l[4];
  __shared__ int   tok_l[4*64]; __shared__ float shi_l[4*64];
  __shared__ int   otok[4*64];  __shared__ float oshi[4*64];
  __shared__ int bbest;

  // ---- prologue / init ----
  if(blk==0){
    const float* hf = enc_out + (long long)(S-1)*HDIM;
    for(int i=t;i<4*HDIM;i+=512) h_cur[i] = hf[i&(HDIM-1)];
    if(t<4){ cum_l[t]=0.f; cur_in[t]=1; }  // SOS=1
    for(int i=t;i<4*64;i+=512){ tok_l[i]=0; shi_l[i]=0.f; }
  }
  int bit = 0;
  gbar2(cnts, rel, ++bit);

  for(int st=0; st<L; ++st){
    // ======== phase A: decoder GRU (block owns 4 dims) ========
    {
      int base = blk*4;
      float xr[4][16];
      if(wave<4){
        int tok[4];
        #pragma unroll
        for(int b=0;b<4;b++) tok[b]=cur_in[b];
        #pragma unroll
        for(int b=0;b<4;b++) load16w(emb,(long long)tok[b]*HDIM+lane*CHK,bf,xr[b]);
        #pragma unroll
        for(int k=0;k<3;k++){
          int idx = wave*3+k; int g=idx>>2, d=idx&3;
          int row = g*HDIM + base + d;
          float w[16]; load16w(Wih,(long long)row*HDIM+lane*CHK,bf,w);
          float a[4]={0.f,0.f,0.f,0.f};
          dot4_accum(w,xr,a);
          float bias = loadscal(bih,row,bf);
          #pragma unroll
          for(int b=0;b<4;b++){
            float v = wred_sum(a[b]);
            if(lane==b) gibuf[idx*4+b] = v + bias;
          }
        }
      } else {
        #pragma unroll
        for(int b=0;b<4;b++) load16f(h_cur+(long long)b*HDIM+lane*CHK, xr[b]);
        #pragma unroll
        for(int k=0;k<3;k++){
          int idx = (wave-4)*3+k; int g=idx>>2, d=idx&3;
          int row = g*HDIM + base + d;
          float w[16]; load16w(Whh,(long long)row*HDIM+lane*CHK,bf,w);
          float a[4]={0.f,0.f,0.f,0.f};
          dot4_accum(w,xr,a);
          float bias = loadscal(bhh,row,bf);
          #pragma unroll
          for(int b=0;b<4;b++){
            float v = wred_sum(a[b]);
            if(lane==b) ghbuf[idx*4+b] = v + bias;
          }
        }
      }
      __syncthreads();
      if(t<16){
        int d=t&3, b=t>>2;
        float ir=gibuf[(0*4+d)*4+b], iz=gibuf[(1*4+d)*4+b], in_=gibuf[(2*4+d)*4+b];
        float hr=ghbuf[(0*4+d)*4+b], hz=ghbuf[(1*4+d)*4+b], hn=ghbuf[(2*4+d)*4+b];
        float r = sigf(ir+hr);
        float z = sigf(iz+hz);
        float n = tanhf(in_ + r*hn);
        float h = h_cur[b*HDIM + base + d];
        hnew[b*HDIM + base + d] = (1.f-z)*n + z*h;
      }
    }
    gbar2(cnts, rel, ++bit);

    // ======== phase B: attention scores (block = seq position) ========
    if(blk < S && wave < 4){
      float x[16]; load16f(hnew+(long long)wave*HDIM+lane*CHK, x);
      float e[16]; load16f(enc_out+(long long)blk*HDIM+lane*CHK, e);
      float a=0.f;
      #pragma unroll
      for(int i=0;i<16;i++) a += x[i]*e[i];
      a = wred_sum(a);
      if(lane==0) scoresb[blk*4+wave] = a;
    }
    gbar2(cnts, rel, ++bit);

    // ======== phase C: softmax + context (blocks 0..7, 128 dims each) ========
    if(blk < 8){
      pbuf[t]       = scoresb[t];
      pbuf[t+512]   = scoresb[t+512];
      __syncthreads();
      if(wave<4){
        int b = wave;
        float v[4];
        #pragma unroll
        for(int k=0;k<4;k++) v[k]=pbuf[(lane+64*k)*4+b];
        float m = fmaxf(fmaxf(v[0],v[1]),fmaxf(v[2],v[3]));
        m = wred_max(m);
        float e[4]; float ss=0.f;
        #pragma unroll
        for(int k=0;k<4;k++){ e[k]=expf(v[k]-m); ss+=e[k]; }
        ss = wred_sum(ss);
        #pragma unroll
        for(int k=0;k<4;k++) pbuf[(lane+64*k)*4+b] = e[k]/ss;
      }
      __syncthreads();
      int hl = t>>2, b = t&3;
      int h = blk*128 + hl;
      float a = 0.f;
      #pragma unroll 8
      for(int s=0;s<256;s++) a += pbuf[s*4+b]*enc_out[(long long)s*HDIM + h];
      ctx[b*HDIM+h] = a;
    }
    gbar2(cnts, rel, ++bit);

    // ======== phase D: concat @ Wc^T, tanh (block owns 4 rows) ========
    {
      int r = blk*4 + (wave>>1);
      int b0 = (wave&1)*2;
      float acc0=0.f, acc1=0.f;
      {
        float w[16]; load16w(Wc,(long long)r*2048 + lane*CHK, bf, w);
        float x0[16], x1[16];
        load16f(hnew+(long long)b0*HDIM+lane*CHK, x0);
        load16f(hnew+(long long)(b0+1)*HDIM+lane*CHK, x1);
        #pragma unroll
        for(int i=0;i<16;i++){ acc0+=w[i]*x0[i]; acc1+=w[i]*x1[i]; }
      }
      {
        float w[16]; load16w(Wc,(long long)r*2048 + 1024 + lane*CHK, bf, w);
        float x0[16], x1[16];
        load16f(ctx+(long long)b0*HDIM+lane*CHK, x0);
        load16f(ctx+(long long)(b0+1)*HDIM+lane*CHK, x1);
        #pragma unroll
        for(int i=0;i<16;i++){ acc0+=w[i]*x0[i]; acc1+=w[i]*x1[i]; }
      }
      acc0 = wred_sum(acc0); acc1 = wred_sum(acc1);
      if(lane==0){
        concat[b0*HDIM + r]     = tanhf(acc0);
        concat[(b0+1)*HDIM + r] = tanhf(acc1);
      }
    }
    gbar2(cnts, rel, ++bit);

    // ======== phase E: Wout logits + per-block online max/sumexp/top4 ========
    {
      float xr[4][16];
      #pragma unroll
      for(int b=0;b<4;b++) load16f(concat+(long long)b*HDIM+lane*CHK, xr[b]);
      int wbase = blk*125;
      int off  = (wave<5) ? wave*16 : 80 + (wave-5)*15;   // 5x16 + 3x15 = 125
      int cnt  = (wave<5) ? 16 : 15;
      float m[4], s[4], tv[4][4]; int ti_[4][4];
      #pragma unroll
      for(int b=0;b<4;b++){
        m[b]=NEG_INF; s[b]=0.f;
        #pragma unroll
        for(int j=0;j<4;j++){ tv[b][j]=NEG_INF; ti_[b][j]=0; }
      }
      for(int k=0;k<cnt;k++){
        int row = wbase + off + k;
        if(row>=V) break;
        float w[16]; load16w(Wout,(long long)row*HDIM+lane*CHK,bf,w);
        float a[4]={0.f,0.f,0.f,0.f};
        dot4_accum(w,xr,a);
        a[0]=wred_sum(a[0]); a[1]=wred_sum(a[1]); a[2]=wred_sum(a[2]); a[3]=wred_sum(a[3]);
        if(lane==0){
          #pragma unroll
          for(int b=0;b<4;b++){
            float v = a[b];
            if(v>m[b]){ s[b]=s[b]*expf(m[b]-v)+1.f; m[b]=v; }
            else s[b] += expf(v-m[b]);
            insert4(tv[b], ti_[b], v, row);
          }
        }
      }
      if(lane==0){
        #pragma unroll
        for(int b=0;b<4;b++){
          lm[wave*4+b]=m[b]; lssum[wave*4+b]=s[b];
          #pragma unroll
          for(int j=0;j<4;j++){ ltv[(wave*4+b)*4+j]=tv[b][j]; lti[(wave*4+b)*4+j]=ti_[b][j]; }
        }
      }
      __syncthreads();
      if(t==0){
        for(int b=0;b<4;b++){
          float M=NEG_INF;
          for(int w=0;w<8;w++) M=fmaxf(M,lm[w*4+b]);
          float Ssum=0.f;
          for(int w=0;w<8;w++) Ssum += lssum[w*4+b]*expf(lm[w*4+b]-M);
          float cv[4]; int ci[4];
          for(int j=0;j<4;j++){ cv[j]=ltv[(0*4+b)*4+j]; ci[j]=lti[(0*4+b)*4+j]; }
          for(int w=1;w<8;w++){
            float vo[4]; int io[4];
            merge4(cv,ci,&ltv[(w*4+b)*4],&lti[(w*4+b)*4],vo,io);
            for(int j=0;j<4;j++){ cv[j]=vo[j]; ci[j]=io[j]; }
          }
          pm[blk*4+b]=M; ps[blk*4+b]=Ssum;
          for(int j=0;j<4;j++){ ptv[(blk*4+b)*4+j]=cv[j]; pti[(blk*4+b)*4+j]=ci[j]; }
        }
      }
    }
    gbar2(cnts, rel, ++bit);

    // ======== phase F: finalize + beam update (block 0) ========
    if(blk==0){
      for(int b=0;b<4;b++){
        float v = (t<256) ? pm[t*4+b] : NEG_INF;
        red[t]=v; __syncthreads();
        for(int sp=256;sp;sp>>=1){ if(t<sp) red[t]=fmaxf(red[t],red[t+sp]); __syncthreads(); }
        float M = red[0]; __syncthreads();
        red[t] = (t<256) ? ps[t*4+b]*expf(v-M) : 0.f; __syncthreads();
        for(int sp=256;sp;sp>>=1){ if(t<sp) red[t]+=red[t+sp]; __syncthreads(); }
        if(t==0) logZ[b]=M+logf(red[0]);
        __syncthreads();
      }
      for(int b=0;b<4;b++){
        if(t<256){
          for(int j=0;j<4;j++){ mtv[t*4+j]=ptv[(t*4+b)*4+j]; mti[t*4+j]=pti[(t*4+b)*4+j]; }
        } else {
          for(int j=0;j<4;j++){ mtv[t*4+j]=NEG_INF; mti[t*4+j]=0; }
        }
        __syncthreads();
        for(int sp=1; sp<512; sp<<=1){
          if((t & (2*sp-1))==0 && t+sp<512){
            float vo[4]; int io[4];
            merge4(&mtv[t*4], &mti[t*4], &mtv[(t+sp)*4], &mti[(t+sp)*4], vo, io);
            for(int j=0;j<4;j++){ mtv[t*4+j]=vo[j]; mti[t*4+j]=io[j]; }
          }
          __syncthreads();
        }
        if(t<4){ tpv[b][t]=mtv[t]-logZ[b]; tpi[b][t]=mti[t]; }
        __syncthreads();
      }
      if(t==0){
        float oc[4];
        for(int b=0;b<4;b++) oc[b]=cum_l[b];
        float cand[16];
        for(int b=0;b<4;b++)
          for(int j=0;j<4;j++){
            bool valid = (st>0)||(b==0);
            cand[b*4+j] = valid ? oc[b]+tpv[b][j] : NEG_INF;
          }
        bool used[16];
        for(int i=0;i<16;i++) used[i]=false;
        for(int q=0;q<4;q++){
          int best=0; float bv=NEG_INF;
          for(int i=0;i<16;i++){ if(!used[i] && cand[i]>bv){ bv=cand[i]; best=i; } }
          used[best]=true;
          int bi = best>>2, jj = best&3;
          l_bi[q]=bi; l_jj[q]=jj; l_tok[q]=tpi[bi][jj]; l_ss[q]=tpv[bi][jj]; l_cum[q]=bv;
        }
      }
      __syncthreads();
      for(int i=t;i<4*L;i+=512){ otok[i]=tok_l[i]; oshi[i]=shi_l[i]; }
      __syncthreads();
      for(int i=t;i<4*L;i+=512){
        int q=i/L, c=i%L;
        int src=l_bi[q];
        tok_l[i] = (c==st)? l_tok[q] : otok[src*L+c];
        shi_l[i] = (c==st)? l_ss[q]  : oshi[src*L+c];
      }
      if(t<4){ cum_l[t]=l_cum[t]; cur_in[t]=l_tok[t]; }
      for(int i=t;i<4*HDIM;i+=512){
        int q=i>>10;
        h_cur[i] = hnew[l_jj[q]*HDIM + (i&(HDIM-1))];
      }
      if(st==L-1){
        if(t==0){
          int bb=0; float bv=l_cum[0];
          for(int b=1;b<4;b++) if(l_cum[b]>bv){ bv=l_cum[b]; bb=b; }
          bbest=bb;
        }
        __syncthreads();
        int bb=bbest;
        for(int c=t;c<L;c+=512){
          float tokv = (float)((c==st)? l_tok[bb] : otok[l_bi[bb]*L+c]);
          float shv  = (c==st)? l_ss[bb] : oshi[l_bi[bb]*L+c];
          if(bf){
            __hip_bfloat16* o = (__hip_bfloat16*)dout;
            o[c]   = __float2bfloat16(tokv);
            o[L+c] = __float2bfloat16(shv);
          } else {
            float* o = (float*)dout;
            o[c]   = tokv;
            o[L+c] = shv;
          }
        }
      }
    }
    gbar2(cnts, rel, ++bit);
  }
}

extern "C" void kernel_launch(void* const* d_in, const int* in_sizes, int n_in,
                              void* d_out, int out_size, void* d_ws, size_t ws_size,
                              hipStream_t stream) {
  const int* seq   = (const int*)d_in[0];
  const void* emb  = d_in[3];
  const void* eWih = d_in[4]; const void* eWhh = d_in[5];
  const void* ebih = d_in[6]; const void* ebhh = d_in[7];
  const void* dWih = d_in[8]; const void* dWhh = d_in[9];
  const void* dbih = d_in[10]; const void* dbhh = d_in[11];
  const void* Wc   = d_in[12]; const void* Wout = d_in[13];

  int S = in_sizes[0];        // 256
  int L = out_size/2;         // 48
  int V = in_sizes[13]/HDIM;  // 32000

  char* p = (char*)d_ws;
  auto carve = [&](size_t bytes)->void* {
    void* r = (void*)p;
    p += (bytes + 255) & ~(size_t)255;
    return r;
  };
  int*   flag    = (int*)  carve(4);
  int*   bar_cnt = (int*)  carve(4);
  int*   dcnts   = (int*)  carve(512*4);   // 8 lines x 64 ints
  int*   drel    = (int*)  carve(64*4);
  float* gi_enc  = (float*)carve((size_t)S*G3*4);
  float* enc_out = (float*)carve((size_t)S*HDIM*4);
  float* h_cur   = (float*)carve(4*HDIM*4);
  float* hnew    = (float*)carve(4*HDIM*4);
  float* scoresb = (float*)carve((size_t)S*4*4);
  float* ctx     = (float*)carve(4*HDIM*4);
  float* concat  = (float*)carve(4*HDIM*4);
  float* pm      = (float*)carve(256*4*4);
  float* ps      = (float*)carve(256*4*4);
  float* ptv     = (float*)carve(256*16*4);
  int*   pti     = (int*)  carve(256*16*4);
  int*   cur_in  = (int*)  carve(4*4);

  k_probe<<<1,256,0,stream>>>((const u16*)emb, flag, bar_cnt, dcnts, drel);
  k_enc_gi<<<(S/4)*8,256,0,stream>>>(seq, emb, eWih, ebih, flag, gi_enc);
  k_enc_persist<<<EB,512,0,stream>>>(eWhh, ebhh, flag, gi_enc, enc_out, S, bar_cnt);
  k_dec_persist<<<DB,512,0,stream>>>(emb, dWih, dWhh, dbih, dbhh, Wc, Wout,
                                     flag, enc_out, S, L, V,
                                     h_cur, hnew, scoresb, ctx, concat,
                                     pm, ps, ptv, pti, cur_in,
                                     dcnts, drel, d_out);
}

// Round 5
// 14684.381 us; speedup vs baseline: 2.2258x; 1.1039x over previous
//
#include <hip/hip_runtime.h>
#include <hip/hip_bf16.h>

#define HDIM 1024
#define G3   3072
#define CHK  16
#define NEG_INF (-__builtin_inff())
#define EB   32    // encoder persistent blocks
#define DB   256   // decoder persistent blocks

typedef unsigned short u16;
typedef unsigned int   u32;

__device__ __forceinline__ float bf2f(u32 h){ union{u32 u; float f;} t; t.u = h<<16; return t.f; }

// ---- uncached (coherence-point) accessors for mutable inter-block data ----
__device__ __forceinline__ float ucldf(const float* p){
  return __hip_atomic_load((float*)p, __ATOMIC_RELAXED, __HIP_MEMORY_SCOPE_AGENT);
}
__device__ __forceinline__ void ucstf(float* p, float v){
  __hip_atomic_store(p, v, __ATOMIC_RELAXED, __HIP_MEMORY_SCOPE_AGENT);
}
__device__ __forceinline__ int ucldi(const int* p){
  return __hip_atomic_load((int*)p, __ATOMIC_RELAXED, __HIP_MEMORY_SCOPE_AGENT);
}
__device__ __forceinline__ void ucsti(int* p, int v){
  __hip_atomic_store(p, v, __ATOMIC_RELAXED, __HIP_MEMORY_SCOPE_AGENT);
}
__device__ __forceinline__ void load16u(const float* p, float* x){
  #pragma unroll
  for(int i=0;i<16;i++) x[i] = ucldf(p+i);
}

__device__ __forceinline__ float wred_sum(float v){
  #pragma unroll
  for(int o=32;o;o>>=1) v += __shfl_xor(v,o,64);
  return v;
}
__device__ __forceinline__ float wred_max(float v){
  #pragma unroll
  for(int o=32;o;o>>=1) v = fmaxf(v,__shfl_xor(v,o,64));
  return v;
}

// load 16 consecutive elements (weights, dtype per flag) into f32 regs
__device__ __forceinline__ void load16w(const void* W, long long eoff, int bf, float* x){
  if(bf){
    const uint4* q = (const uint4*)((const u16*)W + eoff);
    uint4 a = q[0], b = q[1];
    x[0]=bf2f(a.x&0xffffu); x[1]=bf2f(a.x>>16);
    x[2]=bf2f(a.y&0xffffu); x[3]=bf2f(a.y>>16);
    x[4]=bf2f(a.z&0xffffu); x[5]=bf2f(a.z>>16);
    x[6]=bf2f(a.w&0xffffu); x[7]=bf2f(a.w>>16);
    x[8]=bf2f(b.x&0xffffu); x[9]=bf2f(b.x>>16);
    x[10]=bf2f(b.y&0xffffu); x[11]=bf2f(b.y>>16);
    x[12]=bf2f(b.z&0xffffu); x[13]=bf2f(b.z>>16);
    x[14]=bf2f(b.w&0xffffu); x[15]=bf2f(b.w>>16);
  } else {
    const float4* q = (const float4*)((const float*)W + eoff);
    float4 A=q[0],B=q[1],C=q[2],D=q[3];
    x[0]=A.x;x[1]=A.y;x[2]=A.z;x[3]=A.w;
    x[4]=B.x;x[5]=B.y;x[6]=B.z;x[7]=B.w;
    x[8]=C.x;x[9]=C.y;x[10]=C.z;x[11]=C.w;
    x[12]=D.x;x[13]=D.y;x[14]=D.z;x[15]=D.w;
  }
}
__device__ __forceinline__ void load16f(const float* p, float* x){
  const float4* q=(const float4*)p;
  float4 A=q[0],B=q[1],C=q[2],D=q[3];
  x[0]=A.x;x[1]=A.y;x[2]=A.z;x[3]=A.w;
  x[4]=B.x;x[5]=B.y;x[6]=B.z;x[7]=B.w;
  x[8]=C.x;x[9]=C.y;x[10]=C.z;x[11]=C.w;
  x[12]=D.x;x[13]=D.y;x[14]=D.z;x[15]=D.w;
}
__device__ __forceinline__ float loadscal(const void* p, long long i, int bf){
  return bf ? bf2f(((const u16*)p)[i]) : ((const float*)p)[i];
}
__device__ __forceinline__ float sigf(float x){ return 1.f/(1.f+expf(-x)); }

__device__ __forceinline__ void dot4_accum(const float* w, const float xr[4][16], float a[4]){
  #pragma unroll
  for(int i=0;i<16;i++){
    a[0] += w[i]*xr[0][i];
    a[1] += w[i]*xr[1][i];
    a[2] += w[i]*xr[2][i];
    a[3] += w[i]*xr[3][i];
  }
}

// sorted-desc top4 insert, ties -> lower index (jax top_k semantics)
__device__ __forceinline__ void insert4(float* v, int* ix, float nv, int ni){
  bool b3 = (nv>v[3]) || (nv==v[3] && ni<ix[3]);
  if(!b3) return;
  bool b2 = (nv>v[2]) || (nv==v[2] && ni<ix[2]);
  bool b1 = (nv>v[1]) || (nv==v[1] && ni<ix[1]);
  bool b0 = (nv>v[0]) || (nv==v[0] && ni<ix[0]);
  if(b0){ v[3]=v[2];ix[3]=ix[2]; v[2]=v[1];ix[2]=ix[1]; v[1]=v[0];ix[1]=ix[0]; v[0]=nv;ix[0]=ni; }
  else if(b1){ v[3]=v[2];ix[3]=ix[2]; v[2]=v[1];ix[2]=ix[1]; v[1]=nv;ix[1]=ni; }
  else if(b2){ v[3]=v[2];ix[3]=ix[2]; v[2]=nv;ix[2]=ni; }
  else { v[3]=nv; ix[3]=ni; }
}
// merge two sorted-desc top4 lists
__device__ __forceinline__ void merge4(const float* va, const int* ia, const float* vb, const int* ib, float* vo, int* io){
  int pa=0, pb=0;
  for(int k=0;k<4;k++){
    bool ta;
    if(pa>=4) ta=false;
    else if(pb>=4) ta=true;
    else ta = (va[pa]>vb[pb]) || (va[pa]==vb[pb] && ia[pa]<ib[pb]);
    if(ta){ vo[k]=va[pa]; io[k]=ia[pa]; pa++; }
    else  { vo[k]=vb[pb]; io[k]=ib[pb]; pb++; }
  }
}

// fence-free grid barrier (encoder, 32 blocks): pure relaxed atomics.
// Visibility of data: all mutable shared data is accessed with relaxed
// agent-scope atomics (coherence-point accesses); __syncthreads before the
// arrival drains vmcnt(0), so this block's stores are globally visible
// before its arrival is.
__device__ __forceinline__ void gbar(int* cnt, int nblk, int it){
  __syncthreads();
  if(threadIdx.x==0){
    __hip_atomic_fetch_add(cnt, 1, __ATOMIC_RELAXED, __HIP_MEMORY_SCOPE_AGENT);
    while(__hip_atomic_load(cnt, __ATOMIC_RELAXED, __HIP_MEMORY_SCOPE_AGENT) < nblk*it)
      __builtin_amdgcn_s_sleep(4);
  }
  __syncthreads();
}

// fence-free striped grid barrier (decoder, DB=256): 16 arrival lines
// (16 adds each) + release word. No cache-maintenance instructions at all.
__device__ __forceinline__ void gbar2(int* cnts, int* rel, int it){
  __syncthreads();
  if(threadIdx.x==0){
    int g = blockIdx.x & 15;
    __hip_atomic_fetch_add(&cnts[g*16], 1, __ATOMIC_RELAXED, __HIP_MEMORY_SCOPE_AGENT);
    if(blockIdx.x==0){
      #pragma unroll
      for(int g2=0; g2<16; ++g2){
        while(__hip_atomic_load(&cnts[g2*16], __ATOMIC_RELAXED, __HIP_MEMORY_SCOPE_AGENT) < 16*it)
          __builtin_amdgcn_s_sleep(2);
      }
      __hip_atomic_store(rel, it, __ATOMIC_RELAXED, __HIP_MEMORY_SCOPE_AGENT);
    } else {
      while(__hip_atomic_load(rel, __ATOMIC_RELAXED, __HIP_MEMORY_SCOPE_AGENT) < it)
        __builtin_amdgcn_s_sleep(16);
    }
  }
  __syncthreads();
}

// ---------------- dtype probe + barrier zeroing ----------------
__global__ __launch_bounds__(256) void k_probe(const u16* emb, int* flag, int* bar_cnt,
                                               int* dcnts, int* drel){
  __shared__ int cnt;
  if(threadIdx.x==0){ cnt=0; *bar_cnt=0; *drel=0; }
  for(int i=threadIdx.x;i<256;i+=256) dcnts[i]=0;
  __syncthreads();
  int c=0;
  for(int i=threadIdx.x;i<4096;i+=256){
    u32 e = (emb[i]>>7)&0xffu;
    if(e>=0x85u) c++;
  }
  atomicAdd(&cnt,c);
  __syncthreads();
  if(threadIdx.x==0) *flag = (cnt<100)?1:0;  // 1 = bf16, 0 = f32
}

// ---------------- encoder: gi = emb[seq] @ Wih^T + bih (batched over t) ----------------
__global__ __launch_bounds__(256) void k_enc_gi(const int* seq, const void* emb, const void* Wih,
                                                const void* bih, const int* flag, float* gi){
  int bf = *flag;
  int wg = blockIdx.x; int tg = wg>>3, rg = wg&7;
  int wave = threadIdx.x>>6, lane = threadIdx.x&63;
  int tok[4];
  #pragma unroll
  for(int j=0;j<4;j++) tok[j] = seq[tg*4+j];
  float xr[4][16];
  #pragma unroll
  for(int j=0;j<4;j++) load16w(emb, (long long)tok[j]*HDIM + lane*CHK, bf, xr[j]);
  for(int k=0;k<96;k++){
    int row = rg*384 + wave*96 + k;
    float w[16]; load16w(Wih, (long long)row*HDIM + lane*CHK, bf, w);
    float a[4]={0.f,0.f,0.f,0.f};
    dot4_accum(w, xr, a);
    float bias = loadscal(bih, row, bf);
    #pragma unroll
    for(int b=0;b<4;b++){
      float v = wred_sum(a[b]);
      if(lane==b) gi[(long long)(tg*4+b)*G3 + row] = v + bias;
    }
  }
}

// ---------------- persistent encoder recurrence: Whh held in registers ----------------
// All enc_out accesses via relaxed agent atomics (cross-block recurrence).
__global__ __launch_bounds__(512,2) void k_enc_persist(const void* Whh, const void* bhh,
                                                       const int* flag, const float* gi,
                                                       float* enc_out, int S, int* bar_cnt){
  int bf = *flag;
  int wave = threadIdx.x>>6, lane = threadIdx.x&63;
  int dbase = blockIdx.x*32;
  __shared__ float gh_s[96];
  __shared__ float bhh_s[96];
  if(threadIdx.x<96){
    int rl = threadIdx.x;
    int row = (rl>>5)*HDIM + dbase + (rl&31);
    bhh_s[rl] = loadscal(bhh, row, bf);
  }
  float wreg[12][16];
  #pragma unroll
  for(int k=0;k<12;k++){
    int rl = wave*12 + k;
    int row = (rl>>5)*HDIM + dbase + (rl&31);
    load16w(Whh, (long long)row*HDIM + lane*CHK, bf, wreg[k]);
  }
  __syncthreads();

  for(int t=0;t<S;t++){
    if(t>0) gbar(bar_cnt, EB, t);   // enc_out[t-1] fully published
    float h[16];
    if(t>0){
      load16u(enc_out + (long long)(t-1)*HDIM + lane*CHK, h);
    } else {
      #pragma unroll
      for(int i=0;i<16;i++) h[i]=0.f;
    }
    #pragma unroll
    for(int k=0;k<12;k++){
      float a=0.f;
      #pragma unroll
      for(int i=0;i<16;i++) a += wreg[k][i]*h[i];
      a = wred_sum(a);
      if(lane==k) gh_s[wave*12+k] = a + bhh_s[wave*12+k];
    }
    __syncthreads();
    if(threadIdx.x<32){
      int d = threadIdx.x;
      int gd = dbase + d;
      const float* gir = gi + (long long)t*G3;
      float ir = gir[gd], iz = gir[HDIM+gd], in_ = gir[2*HDIM+gd];
      float hr = gh_s[d], hz = gh_s[32+d], hn = gh_s[64+d];
      float r = sigf(ir+hr);
      float z = sigf(iz+hz);
      float n = tanhf(in_ + r*hn);
      float hp = (t>0) ? ucldf(&enc_out[(long long)(t-1)*HDIM + gd]) : 0.f;
      ucstf(&enc_out[(long long)t*HDIM + gd], (1.f-z)*n + z*hp);
    }
  }
}

// ---------------- persistent fused decoder: all 48 steps, 6 phases/step ----------------
__global__ __launch_bounds__(512,2) void k_dec_persist(
    const void* emb, const void* Wih, const void* Whh,
    const void* bih, const void* bhh, const void* Wc, const void* Wout,
    const int* flag, const float* enc_out, int S, int L, int V,
    float* h_cur, float* hnew, float* scoresb, float* ctx, float* concat,
    float* pm, float* ps, float* ptv, int* pti, int* cur_in,
    int* cnts, int* rel, void* dout)
{
  int bf = *flag;
  int t = threadIdx.x;
  int wave = t>>6, lane = t&63;
  int blk = blockIdx.x;

  __shared__ float gibuf[48], ghbuf[48];
  __shared__ float pbuf[1024];
  __shared__ float lm[32], lssum[32], ltv[128]; __shared__ int lti[128];
  // finalize (block 0 only)
  __shared__ float red[512];
  __shared__ float mtv[512*4]; __shared__ int mti[512*4];
  __shared__ float tpv[4][4]; __shared__ int tpi[4][4];
  __shared__ float logZ[4];
  __shared__ int l_bi[4], l_jj[4], l_tok[4]; __shared__ float l_ss[4], l_cum[4];
  __shared__ float cum_l[4];
  __shared__ int   tok_l[4*64]; __shared__ float shi_l[4*64];
  __shared__ int   otok[4*64];  __shared__ float oshi[4*64];
  __shared__ int bbest;

  // ---- prologue / init ----
  if(blk==0){
    const float* hf = enc_out + (long long)(S-1)*HDIM;
    for(int i=t;i<4*HDIM;i+=512) ucstf(&h_cur[i], hf[i&(HDIM-1)]);
    if(t<4){ cum_l[t]=0.f; ucsti(&cur_in[t], 1); }  // SOS=1
    for(int i=t;i<4*64;i+=512){ tok_l[i]=0; shi_l[i]=0.f; }
  }
  int bit = 0;
  gbar2(cnts, rel, ++bit);

  for(int st=0; st<L; ++st){
    // ======== phase A: decoder GRU (block owns 4 dims) ========
    {
      int base = blk*4;
      float xr[4][16];
      if(wave<4){
        int tok[4];
        #pragma unroll
        for(int b=0;b<4;b++) tok[b]=ucldi(&cur_in[b]);
        #pragma unroll
        for(int b=0;b<4;b++) load16w(emb,(long long)tok[b]*HDIM+lane*CHK,bf,xr[b]);
        #pragma unroll
        for(int k=0;k<3;k++){
          int idx = wave*3+k; int g=idx>>2, d=idx&3;
          int row = g*HDIM + base + d;
          float w[16]; load16w(Wih,(long long)row*HDIM+lane*CHK,bf,w);
          float a[4]={0.f,0.f,0.f,0.f};
          dot4_accum(w,xr,a);
          float bias = loadscal(bih,row,bf);
          #pragma unroll
          for(int b=0;b<4;b++){
            float v = wred_sum(a[b]);
            if(lane==b) gibuf[idx*4+b] = v + bias;
          }
        }
      } else {
        #pragma unroll
        for(int b=0;b<4;b++) load16u(h_cur+(long long)b*HDIM+lane*CHK, xr[b]);
        #pragma unroll
        for(int k=0;k<3;k++){
          int idx = (wave-4)*3+k; int g=idx>>2, d=idx&3;
          int row = g*HDIM + base + d;
          float w[16]; load16w(Whh,(long long)row*HDIM+lane*CHK,bf,w);
          float a[4]={0.f,0.f,0.f,0.f};
          dot4_accum(w,xr,a);
          float bias = loadscal(bhh,row,bf);
          #pragma unroll
          for(int b=0;b<4;b++){
            float v = wred_sum(a[b]);
            if(lane==b) ghbuf[idx*4+b] = v + bias;
          }
        }
      }
      __syncthreads();
      if(t<16){
        int d=t&3, b=t>>2;
        float ir=gibuf[(0*4+d)*4+b], iz=gibuf[(1*4+d)*4+b], in_=gibuf[(2*4+d)*4+b];
        float hr=ghbuf[(0*4+d)*4+b], hz=ghbuf[(1*4+d)*4+b], hn=ghbuf[(2*4+d)*4+b];
        float r = sigf(ir+hr);
        float z = sigf(iz+hz);
        float n = tanhf(in_ + r*hn);
        float h = ucldf(&h_cur[b*HDIM + base + d]);
        ucstf(&hnew[b*HDIM + base + d], (1.f-z)*n + z*h);
      }
    }
    gbar2(cnts, rel, ++bit);

    // ======== phase B: attention scores (block = seq position) ========
    if(blk < S && wave < 4){
      float x[16]; load16u(hnew+(long long)wave*HDIM+lane*CHK, x);
      float e[16]; load16f(enc_out+(long long)blk*HDIM+lane*CHK, e);
      float a=0.f;
      #pragma unroll
      for(int i=0;i<16;i++) a += x[i]*e[i];
      a = wred_sum(a);
      if(lane==0) ucstf(&scoresb[blk*4+wave], a);
    }
    gbar2(cnts, rel, ++bit);

    // ======== phase C: softmax + context (blocks 0..7, 128 dims each) ========
    if(blk < 8){
      pbuf[t]     = ucldf(&scoresb[t]);
      pbuf[t+512] = ucldf(&scoresb[t+512]);
      __syncthreads();
      if(wave<4){
        int b = wave;
        float v[4];
        #pragma unroll
        for(int k=0;k<4;k++) v[k]=pbuf[(lane+64*k)*4+b];
        float m = fmaxf(fmaxf(v[0],v[1]),fmaxf(v[2],v[3]));
        m = wred_max(m);
        float e[4]; float ss=0.f;
        #pragma unroll
        for(int k=0;k<4;k++){ e[k]=expf(v[k]-m); ss+=e[k]; }
        ss = wred_sum(ss);
        #pragma unroll
        for(int k=0;k<4;k++) pbuf[(lane+64*k)*4+b] = e[k]/ss;
      }
      __syncthreads();
      int hl = t>>2, b = t&3;
      int h = blk*128 + hl;
      float a = 0.f;
      #pragma unroll 8
      for(int s=0;s<256;s++) a += pbuf[s*4+b]*enc_out[(long long)s*HDIM + h];
      ucstf(&ctx[b*HDIM+h], a);
    }
    gbar2(cnts, rel, ++bit);

    // ======== phase D: concat @ Wc^T, tanh (block owns 4 rows) ========
    {
      int r = blk*4 + (wave>>1);
      int b0 = (wave&1)*2;
      float acc0=0.f, acc1=0.f;
      {
        float w[16]; load16w(Wc,(long long)r*2048 + lane*CHK, bf, w);
        float x0[16], x1[16];
        load16u(hnew+(long long)b0*HDIM+lane*CHK, x0);
        load16u(hnew+(long long)(b0+1)*HDIM+lane*CHK, x1);
        #pragma unroll
        for(int i=0;i<16;i++){ acc0+=w[i]*x0[i]; acc1+=w[i]*x1[i]; }
      }
      {
        float w[16]; load16w(Wc,(long long)r*2048 + 1024 + lane*CHK, bf, w);
        float x0[16], x1[16];
        load16u(ctx+(long long)b0*HDIM+lane*CHK, x0);
        load16u(ctx+(long long)(b0+1)*HDIM+lane*CHK, x1);
        #pragma unroll
        for(int i=0;i<16;i++){ acc0+=w[i]*x0[i]; acc1+=w[i]*x1[i]; }
      }
      acc0 = wred_sum(acc0); acc1 = wred_sum(acc1);
      if(lane==0){
        ucstf(&concat[b0*HDIM + r],     tanhf(acc0));
        ucstf(&concat[(b0+1)*HDIM + r], tanhf(acc1));
      }
    }
    gbar2(cnts, rel, ++bit);

    // ======== phase E: Wout logits + per-block online max/sumexp/top4 ========
    {
      float xr[4][16];
      #pragma unroll
      for(int b=0;b<4;b++) load16u(concat+(long long)b*HDIM+lane*CHK, xr[b]);
      int wbase = blk*125;
      int off  = (wave<5) ? wave*16 : 80 + (wave-5)*15;   // 5x16 + 3x15 = 125
      int cnt  = (wave<5) ? 16 : 15;
      float m[4], s[4], tv[4][4]; int ti_[4][4];
      #pragma unroll
      for(int b=0;b<4;b++){
        m[b]=NEG_INF; s[b]=0.f;
        #pragma unroll
        for(int j=0;j<4;j++){ tv[b][j]=NEG_INF; ti_[b][j]=0; }
      }
      for(int k=0;k<cnt;k++){
        int row = wbase + off + k;
        if(row>=V) break;
        float w[16]; load16w(Wout,(long long)row*HDIM+lane*CHK,bf,w);
        float a[4]={0.f,0.f,0.f,0.f};
        dot4_accum(w,xr,a);
        a[0]=wred_sum(a[0]); a[1]=wred_sum(a[1]); a[2]=wred_sum(a[2]); a[3]=wred_sum(a[3]);
        if(lane==0){
          #pragma unroll
          for(int b=0;b<4;b++){
            float v = a[b];
            if(v>m[b]){ s[b]=s[b]*expf(m[b]-v)+1.f; m[b]=v; }
            else s[b] += expf(v-m[b]);
            insert4(tv[b], ti_[b], v, row);
          }
        }
      }
      if(lane==0){
        #pragma unroll
        for(int b=0;b<4;b++){
          lm[wave*4+b]=m[b]; lssum[wave*4+b]=s[b];
          #pragma unroll
          for(int j=0;j<4;j++){ ltv[(wave*4+b)*4+j]=tv[b][j]; lti[(wave*4+b)*4+j]=ti_[b][j]; }
        }
      }
      __syncthreads();
      if(t==0){
        for(int b=0;b<4;b++){
          float M=NEG_INF;
          for(int w=0;w<8;w++) M=fmaxf(M,lm[w*4+b]);
          float Ssum=0.f;
          for(int w=0;w<8;w++) Ssum += lssum[w*4+b]*expf(lm[w*4+b]-M);
          float cv[4]; int ci[4];
          for(int j=0;j<4;j++){ cv[j]=ltv[(0*4+b)*4+j]; ci[j]=lti[(0*4+b)*4+j]; }
          for(int w=1;w<8;w++){
            float vo[4]; int io[4];
            merge4(cv,ci,&ltv[(w*4+b)*4],&lti[(w*4+b)*4],vo,io);
            for(int j=0;j<4;j++){ cv[j]=vo[j]; ci[j]=io[j]; }
          }
          ucstf(&pm[blk*4+b], M); ucstf(&ps[blk*4+b], Ssum);
          for(int j=0;j<4;j++){ ucstf(&ptv[(blk*4+b)*4+j], cv[j]); ucsti(&pti[(blk*4+b)*4+j], ci[j]); }
        }
      }
    }
    gbar2(cnts, rel, ++bit);

    // ======== phase F: finalize + beam update (block 0) ========
    if(blk==0){
      for(int b=0;b<4;b++){
        float v = (t<256) ? ucldf(&pm[t*4+b]) : NEG_INF;
        red[t]=v; __syncthreads();
        for(int sp=256;sp;sp>>=1){ if(t<sp) red[t]=fmaxf(red[t],red[t+sp]); __syncthreads(); }
        float M = red[0]; __syncthreads();
        red[t] = (t<256) ? ucldf(&ps[t*4+b])*expf(v-M) : 0.f; __syncthreads();
        for(int sp=256;sp;sp>>=1){ if(t<sp) red[t]+=red[t+sp]; __syncthreads(); }
        if(t==0) logZ[b]=M+logf(red[0]);
        __syncthreads();
      }
      for(int b=0;b<4;b++){
        if(t<256){
          for(int j=0;j<4;j++){ mtv[t*4+j]=ucldf(&ptv[(t*4+b)*4+j]); mti[t*4+j]=ucldi(&pti[(t*4+b)*4+j]); }
        } else {
          for(int j=0;j<4;j++){ mtv[t*4+j]=NEG_INF; mti[t*4+j]=0; }
        }
        __syncthreads();
        for(int sp=1; sp<512; sp<<=1){
          if((t & (2*sp-1))==0 && t+sp<512){
            float vo[4]; int io[4];
            merge4(&mtv[t*4], &mti[t*4], &mtv[(t+sp)*4], &mti[(t+sp)*4], vo, io);
            for(int j=0;j<4;j++){ mtv[t*4+j]=vo[j]; mti[t*4+j]=io[j]; }
          }
          __syncthreads();
        }
        if(t<4){ tpv[b][t]=mtv[t]-logZ[b]; tpi[b][t]=mti[t]; }
        __syncthreads();
      }
      if(t==0){
        float oc[4];
        for(int b=0;b<4;b++) oc[b]=cum_l[b];
        float cand[16];
        for(int b=0;b<4;b++)
          for(int j=0;j<4;j++){
            bool valid = (st>0)||(b==0);
            cand[b*4+j] = valid ? oc[b]+tpv[b][j] : NEG_INF;
          }
        bool used[16];
        for(int i=0;i<16;i++) used[i]=false;
        for(int q=0;q<4;q++){
          int best=0; float bv=NEG_INF;
          for(int i=0;i<16;i++){ if(!used[i] && cand[i]>bv){ bv=cand[i]; best=i; } }
          used[best]=true;
          int bi = best>>2, jj = best&3;
          l_bi[q]=bi; l_jj[q]=jj; l_tok[q]=tpi[bi][jj]; l_ss[q]=tpv[bi][jj]; l_cum[q]=bv;
        }
      }
      __syncthreads();
      for(int i=t;i<4*L;i+=512){ otok[i]=tok_l[i]; oshi[i]=shi_l[i]; }
      __syncthreads();
      for(int i=t;i<4*L;i+=512){
        int q=i/L, c=i%L;
        int src=l_bi[q];
        tok_l[i] = (c==st)? l_tok[q] : otok[src*L+c];
        shi_l[i] = (c==st)? l_ss[q]  : oshi[src*L+c];
      }
      if(t<4){ cum_l[t]=l_cum[t]; ucsti(&cur_in[t], l_tok[t]); }
      for(int i=t;i<4*HDIM;i+=512){
        int q=i>>10;
        ucstf(&h_cur[i], ucldf(&hnew[l_jj[q]*HDIM + (i&(HDIM-1))]));
      }
      if(st==L-1){
        if(t==0){
          int bb=0; float bv=l_cum[0];
          for(int b=1;b<4;b++) if(l_cum[b]>bv){ bv=l_cum[b]; bb=b; }
          bbest=bb;
        }
        __syncthreads();
        int bb=bbest;
        for(int c=t;c<L;c+=512){
          float tokv = (float)((c==st)? l_tok[bb] : otok[l_bi[bb]*L+c]);
          float shv  = (c==st)? l_ss[bb] : oshi[l_bi[bb]*L+c];
          if(bf){
            __hip_bfloat16* o = (__hip_bfloat16*)dout;
            o[c]   = __float2bfloat16(tokv);
            o[L+c] = __float2bfloat16(shv);
          } else {
            float* o = (float*)dout;
            o[c]   = tokv;
            o[L+c] = shv;
          }
        }
      }
    }
    gbar2(cnts, rel, ++bit);
  }
}

extern "C" void kernel_launch(void* const* d_in, const int* in_sizes, int n_in,
                              void* d_out, int out_size, void* d_ws, size_t ws_size,
                              hipStream_t stream) {
  const int* seq   = (const int*)d_in[0];
  const void* emb  = d_in[3];
  const void* eWih = d_in[4]; const void* eWhh = d_in[5];
  const void* ebih = d_in[6]; const void* ebhh = d_in[7];
  const void* dWih = d_in[8]; const void* dWhh = d_in[9];
  const void* dbih = d_in[10]; const void* dbhh = d_in[11];
  const void* Wc   = d_in[12]; const void* Wout = d_in[13];

  int S = in_sizes[0];        // 256
  int L = out_size/2;         // 48
  int V = in_sizes[13]/HDIM;  // 32000

  char* p = (char*)d_ws;
  auto carve = [&](size_t bytes)->void* {
    void* r = (void*)p;
    p += (bytes + 255) & ~(size_t)255;
    return r;
  };
  int*   flag    = (int*)  carve(4);
  int*   bar_cnt = (int*)  carve(4);
  int*   dcnts   = (int*)  carve(256*4);   // 16 lines x 16 ints
  int*   drel    = (int*)  carve(64*4);
  float* gi_enc  = (float*)carve((size_t)S*G3*4);
  float* enc_out = (float*)carve((size_t)S*HDIM*4);
  float* h_cur   = (float*)carve(4*HDIM*4);
  float* hnew    = (float*)carve(4*HDIM*4);
  float* scoresb = (float*)carve((size_t)S*4*4);
  float* ctx     = (float*)carve(4*HDIM*4);
  float* concat  = (float*)carve(4*HDIM*4);
  float* pm      = (float*)carve(256*4*4);
  float* ps      = (float*)carve(256*4*4);
  float* ptv     = (float*)carve(256*16*4);
  int*   pti     = (int*)  carve(256*16*4);
  int*   cur_in  = (int*)  carve(4*4);

  k_probe<<<1,256,0,stream>>>((const u16*)emb, flag, bar_cnt, dcnts, drel);
  k_enc_gi<<<(S/4)*8,256,0,stream>>>(seq, emb, eWih, ebih, flag, gi_enc);
  k_enc_persist<<<EB,512,0,stream>>>(eWhh, ebhh, flag, gi_enc, enc_out, S, bar_cnt);
  k_dec_persist<<<DB,512,0,stream>>>(emb, dWih, dWhh, dbih, dbhh, Wc, Wout,
                                     flag, enc_out, S, L, V,
                                     h_cur, hnew, scoresb, ctx, concat,
                                     pm, ps, ptv, pti, cur_in,
                                     dcnts, drel, d_out);
}